// Round 3
// baseline (180.608 us; speedup 1.0000x reference)
//
#include <hip/hip_runtime.h>
#include <math.h>

#define EPSF 1e-4f
#define NB_L1 256
#define NB_L0 1024
#define NBLK (1 + NB_L1 + NB_L0)

// Fast sigmoid+clip for the bulk neg path: v_exp + v_rcp (monotone, ~1ulp each).
static __device__ __forceinline__ float sigmoid_fast(float x) {
    float e = __expf(-x);
    float p = __builtin_amdgcn_rcpf(1.0f + e);
    return fminf(fmaxf(p, EPSF), 1.0f - EPSF);
}
// Precise versions for the 256-coord pos path (threshold-crossing sensitive).
static __device__ __forceinline__ float sigmoid_precise(float x) {
    float p = 1.0f / (1.0f + expf(-x));
    return fminf(fmaxf(p, EPSF), 1.0f - EPSF);
}
static __device__ __forceinline__ float softplus(float x) {
    return fmaxf(x, 0.0f) + log1pf(expf(-fabsf(x)));
}

// max over 3x3 (h,w) patch at halo-depth row rd, halo-h hh, lane column tx
template <int W>
static __device__ __forceinline__ float hmax3(const float* pm, int rd, int hh, int tx) {
    constexpr int LW = W + 2;
    const float* p = pm + (rd * 10 + hh) * LW + tx;
    float a = fmaxf(fmaxf(p[0], p[1]), p[2]);
    float b = fmaxf(fmaxf(p[LW], p[LW + 1]), p[LW + 2]);
    float c = fmaxf(fmaxf(p[2 * LW], p[2 * LW + 1]), p[2 * LW + 2]);
    return fmaxf(fmaxf(a, b), c);
}

// Tile: TD(d) x 8(h) x full-W. Block = W*TY = 512 threads.
// pm halo tile: (TD+2) x 10 x (W+2); w-halo cols are OOB => -inf.
template <int W, int TY, int TD>
static __device__ void neg_tile(const float* __restrict__ logits,
                                const float* __restrict__ gtprob,
                                int D, int H, int tileIdx, float* pm,
                                double& lsum, double& csum) {
    constexpr int LW = W + 2;
    constexpr int NROW = (TD + 2) * 10;
    const int A = 2;
    const int nh = H / 8, nd = D / TD;
    int ht = tileIdx % nh;
    int rest = tileIdx / nh;
    int dt = rest % nd;
    int ab = rest / nd;
    int a = ab & 1, b = ab >> 1;
    int h0 = ht * 8, d0 = dt * TD;
    size_t HW = (size_t)H * W;
    size_t vol = (size_t)D * HW;
    const float* lg = logits + ((size_t)b * 4 * A + a) * vol;  // channel = cls*A + a
    size_t cs = (size_t)A * vol;
    const float* gtb = gtprob + ((size_t)b * A + a) * vol;
    int tid = threadIdx.x;
    int tx = tid % W, ty = tid / W;

    // Halo fill: coalesced W-float rows; max over classes BEFORE sigmoid (monotone).
    for (int r = ty; r < NROW; r += TY) {
        int dd = r / 10, hh = r - dd * 10;
        int d = d0 + dd - 1, h = h0 + hh - 1;
        float v = -INFINITY;
        if ((unsigned)d < (unsigned)D && (unsigned)h < (unsigned)H) {
            size_t off = (size_t)d * HW + (size_t)h * W + tx;
            float x = fmaxf(fmaxf(lg[off], lg[off + cs]),
                            fmaxf(lg[off + 2 * cs], lg[off + 3 * cs]));
            v = sigmoid_fast(x);
        }
        pm[r * LW + tx + 1] = v;
        if (tx < 2) pm[r * LW + tx * (W + 1)] = -INFINITY;
    }
    __syncthreads();

    for (int hh = ty; hh < 8; hh += TY) {
        float gtv[TD];
#pragma unroll
        for (int dd = 0; dd < TD; dd++)
            gtv[dd] = gtb[(size_t)(d0 + dd) * HW + (size_t)(h0 + hh) * W + tx];
        // rolling 3-plane window of (h,w)-maxes
        float hm0 = hmax3<W>(pm, 0, hh, tx);
        float hm1 = hmax3<W>(pm, 1, hh, tx);
#pragma unroll
        for (int dd = 0; dd < TD; dd++) {
            float hm2 = hmax3<W>(pm, dd + 2, hh, tx);
            float mx = fmaxf(fmaxf(hm0, hm1), hm2);
            float pmc = pm[((dd + 1) * 10 + hh + 1) * LW + tx + 1];
            if (gtv[dd] == -1.0f && mx == pmc && pmc > EPSF) {
                lsum += (double)(-__logf(1.0f - pmc) * pmc);
                csum += (double)pmc;
            }
            hm0 = hm1; hm1 = hm2;
        }
    }
}

// ws layout: [0..63] counter (zeroed by memset); slots at +64: NBLK x 6 doubles
// slot order: [loss_pos, loss_neg, loss_other, count_pos, count_neg, count_other]
__global__ __launch_bounds__(512) void fused_kernel(
    const float* __restrict__ lg0, const float* __restrict__ gt0, const int* __restrict__ c0,
    const float* __restrict__ lg1, const float* __restrict__ gt1, const int* __restrict__ c1,
    const float* __restrict__ wcls, double* __restrict__ slots,
    unsigned* __restrict__ counter, float* __restrict__ out) {
    __shared__ float pm[60 * 130];
    __shared__ double spart[48];
    __shared__ unsigned present[4];
    __shared__ bool isLast;
    int tid = threadIdx.x;
    int bid = blockIdx.x;
    double v0 = 0, v1 = 0, v2 = 0, v3 = 0, v4 = 0, v5 = 0;

    if (bid == 0) {
        // ---- pos path: both levels, 128 active threads ----
        if (tid < 4) present[tid] = 0u;
        __syncthreads();
        int lvl = (tid >> 6) & 1, tt = tid & 63;
        int b = tt >> 5, k = tt & 31;
        const float* lg = lvl ? lg1 : lg0;
        const float* gt = lvl ? gt1 : gt0;
        const int* cd = lvl ? c1 : c0;
        int D = lvl ? 32 : 64, H = lvl ? 64 : 128, Wd = lvl ? 64 : 128;
        int a = 0, d = 0, h = 0, w = 0, cls = 0;
        bool valid = false;
        size_t vol = (size_t)D * H * Wd, off = 0;
        if (tid < 128) {
            const int* c = cd + ((size_t)b * 32 + k) * 4;
            a = c[0]; d = c[1]; h = c[2]; w = c[3];
            valid = a > -1;
            if (!valid) { a = 0; d = 0; h = 0; w = 0; }
            off = ((size_t)d * H + h) * (size_t)Wd + w;
            float gval = gt[((size_t)b * 2 + a) * vol + off];
            cls = (int)gval - 1;
            cls = cls < 0 ? 0 : (cls > 3 ? 3 : cls);
            if (valid) atomicOr(&present[lvl * 2 + b], 1u << cls);
        }
        __syncthreads();
        if (tid < 128) {
            unsigned pmask = present[lvl * 2 + b];
            float vm = valid ? 1.0f : 0.0f;
            const float* lgb = lg + (size_t)b * 8 * vol;
            size_t aoff = (size_t)a * vol + off;
            float l_t = lgb[(size_t)cls * 2 * vol + aoff];
            float p_t = sigmoid_precise(l_t);
            float w_pos = (1.0f - p_t) * wcls[cls] * vm;
            float loss_pos = softplus(-l_t) * w_pos;  // -log_sigmoid(l_t)
            float ptg = (p_t > 0.5f) ? 1.0f : 0.0f;
            float lo = 0.0f, co = 0.0f;
#pragma unroll
            for (int cc = 0; cc < 4; cc++) {
                float l_o = lgb[(size_t)cc * 2 * vol + aoff];
                float p_o = sigmoid_precise(l_o);
                float wo = fmaxf(p_o - (p_t - 0.05f), 0.0f) * ((p_o > 0.5f) ? 1.0f : 0.0f) * ptg;
                float pres = ((pmask >> cc) & 1u) ? 1.0f : 0.0f;
                wo *= (1.0f - pres) * vm;
                lo += softplus(l_o) * wo;  // -log_sigmoid(-l_o)
                co += wo;
            }
            v0 = loss_pos; v3 = w_pos; v2 = lo; v5 = co;
        }
    } else if (bid <= NB_L1) {
        neg_tile<64, 8, 4>(lg1, gt1, 32, 64, bid - 1, pm, v1, v4);
    } else {
        neg_tile<128, 4, 4>(lg0, gt0, 64, 128, bid - 1 - NB_L1, pm, v1, v4);
    }

    // ---- block reduction (double) ----
    for (int o = 32; o > 0; o >>= 1) {
        v0 += __shfl_down(v0, o); v1 += __shfl_down(v1, o); v2 += __shfl_down(v2, o);
        v3 += __shfl_down(v3, o); v4 += __shfl_down(v4, o); v5 += __shfl_down(v5, o);
    }
    int wave = tid >> 6, lane = tid & 63;
    if (lane == 0) {
        double* sp = spart + wave * 6;
        sp[0] = v0; sp[1] = v1; sp[2] = v2; sp[3] = v3; sp[4] = v4; sp[5] = v5;
    }
    __syncthreads();
    if (tid == 0) {
        double s[6] = {0, 0, 0, 0, 0, 0};
#pragma unroll
        for (int wv = 0; wv < 8; wv++)
#pragma unroll
            for (int j = 0; j < 6; j++) s[j] += spart[wv * 6 + j];
        double* slot = slots + (size_t)bid * 6;
#pragma unroll
        for (int j = 0; j < 6; j++) slot[j] = s[j];
        __threadfence();
        unsigned prev = atomicAdd(counter, 1u);
        isLast = (prev == NBLK - 1);
    }
    __syncthreads();
    if (isLast) {
        // last block: sum all slots, write output
        __threadfence();
        double acc[6] = {0, 0, 0, 0, 0, 0};
        for (int i = tid; i < NBLK; i += 512) {
            const double* sl = slots + (size_t)i * 6;
#pragma unroll
            for (int j = 0; j < 6; j++) acc[j] += sl[j];
        }
#pragma unroll
        for (int j = 0; j < 6; j++)
            for (int o = 32; o > 0; o >>= 1) acc[j] += __shfl_down(acc[j], o);
        __syncthreads();  // spart reuse
        if (lane == 0) {
            double* sp = spart + wave * 6;
#pragma unroll
            for (int j = 0; j < 6; j++) sp[j] = acc[j];
        }
        __syncthreads();
        if (tid == 0) {
#pragma unroll
            for (int j = 0; j < 6; j++) {
                double s = 0;
#pragma unroll
                for (int wv = 0; wv < 8; wv++) s += spart[wv * 6 + j];
                out[j] = (float)s;
            }
        }
    }
}

extern "C" void kernel_launch(void* const* d_in, const int* in_sizes, int n_in,
                              void* d_out, int out_size, void* d_ws, size_t ws_size,
                              hipStream_t stream) {
    const float *logits0 = nullptr, *gtprob0 = nullptr, *logits1 = nullptr,
                *gtprob1 = nullptr, *wcls = nullptr;
    const int *coords0 = nullptr, *coords1 = nullptr;
    for (int i = 0; i < n_in; i++) {
        switch (in_sizes[i]) {
            case 16777216: logits0 = (const float*)d_in[i]; break;   // 2*8*64*128*128
            case 4194304:  gtprob0 = (const float*)d_in[i]; break;   // 2*2*64*128*128
            case 2097152:  logits1 = (const float*)d_in[i]; break;   // 2*8*32*64*64
            case 524288:   gtprob1 = (const float*)d_in[i]; break;   // 2*2*32*64*64
            case 4:        wcls    = (const float*)d_in[i]; break;
            case 256:
                if (!coords0) coords0 = (const int*)d_in[i];
                else          coords1 = (const int*)d_in[i];
                break;
        }
    }
    unsigned* counter = (unsigned*)d_ws;
    double* slots = (double*)((char*)d_ws + 64);
    hipMemsetAsync(d_ws, 0, 64, stream);  // zero the completion counter only
    fused_kernel<<<NBLK, 512, 0, stream>>>(logits0, gtprob0, coords0,
                                           logits1, gtprob1, coords1,
                                           wcls, slots, counter, (float*)d_out);
}

// Round 4
// 163.697 us; speedup vs baseline: 1.1033x; 1.1033x over previous
//
#include <hip/hip_runtime.h>
#include <math.h>

#define EPSF 1e-4f
#define NBLK 1024

static __device__ __forceinline__ float sigmoid_fast(float x) {
    float e = __expf(-x);
    float p = __builtin_amdgcn_rcpf(1.0f + e);
    return fminf(fmaxf(p, EPSF), 1.0f - EPSF);
}
static __device__ __forceinline__ float sigmoid_precise(float x) {
    float p = 1.0f / (1.0f + expf(-x));
    return fminf(fmaxf(p, EPSF), 1.0f - EPSF);
}
static __device__ __forceinline__ float softplus(float x) {
    return fmaxf(x, 0.0f) + log1pf(expf(-fabsf(x)));
}
static __device__ __forceinline__ float4 fmax4(float4 a, float4 b) {
    float4 r;
    r.x = fmaxf(a.x, b.x); r.y = fmaxf(a.y, b.y);
    r.z = fmaxf(a.z, b.z); r.w = fmaxf(a.w, b.w);
    return r;
}
static __device__ __forceinline__ float4 sig4(float4 x) {
    float4 r;
    r.x = sigmoid_fast(x.x); r.y = sigmoid_fast(x.y);
    r.z = sigmoid_fast(x.z); r.w = sigmoid_fast(x.w);
    return r;
}

// w-window max (3-wide) of a quad from LDS row; w-neighbors via lane shuffles.
// WG lanes per row; group-edge lanes are true tensor edges (full-W tiles) => -inf.
template <int WG, int Wc>
static __device__ __forceinline__ float4 wmax_row(const float* pm, int row, int w0) {
    const float4 v = *(const float4*)(pm + (size_t)row * Wc + 4 * w0);
    float lft = __shfl_up(v.w, 1);
    float rgt = __shfl_down(v.x, 1);
    lft = (w0 == 0) ? -INFINITY : lft;
    rgt = (w0 == WG - 1) ? -INFINITY : rgt;
    float4 r;
    r.x = fmaxf(fmaxf(lft, v.x), v.y);
    r.y = fmaxf(fmaxf(v.x, v.y), v.z);
    r.z = fmaxf(fmaxf(v.y, v.z), v.w);
    r.w = fmaxf(fmaxf(v.z, v.w), rgt);
    return r;
}
// fold 3 consecutive h-rows (same d) of w-maxes
template <int WG, int Wc>
static __device__ __forceinline__ float4 hfold(const float* pm, int row0, int w0) {
    return fmax4(fmax4(wmax_row<WG, Wc>(pm, row0, w0), wmax_row<WG, Wc>(pm, row0 + 1, w0)),
                 wmax_row<WG, Wc>(pm, row0 + 2, w0));
}

// One neg-path tile: TD(d) x TH(h) x Wc(w). 512 threads.
// pm rows indexed rd*(TH+2)+rh, rd in [0,TD+2), rh in [0,TH+2), row = Wc floats.
// Tile decode assumes D/TD == 16 and H/TH == 16 (true for both levels' configs).
template <int Wc, int TD, int TH>
static __device__ void neg_tile(const float* __restrict__ logits,
                                const float* __restrict__ gtprob,
                                int D, int H, int tileIdx, float* pm,
                                double& lsum, double& csum) {
    constexpr int WG = Wc / 4;          // lane groups across w
    constexpr int NROWH = TH + 2;
    constexpr int NROW = (TD + 2) * NROWH;
    constexpr int RPP = 512 / WG;       // fill rows per pass
    constexpr int G = 512 / WG;         // compute thread-groups
    const int ht = tileIdx & 15, dt = (tileIdx >> 4) & 15, ab = tileIdx >> 8;
    const int a = ab & 1, b = ab >> 1;
    const int h0 = ht * TH, d0 = dt * TD;
    size_t HW = (size_t)H * Wc;
    size_t vol = (size_t)D * HW;
    const float* lg = logits + ((size_t)b * 8 + a) * vol;  // channel = cls*2 + a
    const size_t cs = 2 * vol;
    const float* gtb = gtprob + ((size_t)b * 2 + a) * vol;
    const int tid = threadIdx.x;
    const int w0 = tid % WG, rg = tid / WG;

    // ---- fill: sigmoid(max over 4 classes of logits), float4-wide ----
#pragma unroll
    for (int r = rg; r < NROW; r += RPP) {
        int rd = r / NROWH, rh = r - rd * NROWH;
        int d = d0 + rd - 1, h = h0 + rh - 1;
        float4 v = make_float4(-INFINITY, -INFINITY, -INFINITY, -INFINITY);
        if ((unsigned)d < (unsigned)D && (unsigned)h < (unsigned)H) {
            const float* p0 = lg + (size_t)d * HW + (size_t)h * Wc + 4 * w0;
            float4 c0 = *(const float4*)(p0);
            float4 c1 = *(const float4*)(p0 + cs);
            float4 c2 = *(const float4*)(p0 + 2 * cs);
            float4 c3 = *(const float4*)(p0 + 3 * cs);
            v = sig4(fmax4(fmax4(c0, c1), fmax4(c2, c3)));
        }
        *(float4*)(pm + (size_t)r * Wc + 4 * w0) = v;
    }
    __syncthreads();

    // ---- compute: per cell (dd,hh), 3x3x3 max filter over quads ----
    for (int cidx = rg; cidx < TD * TH; cidx += G) {
        int dd = cidx / TH, hh = cidx - dd * TH;
        float4 hm0 = hfold<WG, Wc>(pm, (dd + 0) * NROWH + hh, w0);
        float4 hm1 = hfold<WG, Wc>(pm, (dd + 1) * NROWH + hh, w0);
        float4 hm2 = hfold<WG, Wc>(pm, (dd + 2) * NROWH + hh, w0);
        float4 mx = fmax4(fmax4(hm0, hm1), hm2);
        float4 pc = *(const float4*)(pm + (size_t)((dd + 1) * NROWH + hh + 1) * Wc + 4 * w0);
        const float* gp = gtb + (size_t)(d0 + dd) * HW + (size_t)(h0 + hh) * Wc + 4 * w0;
        float4 g = *(const float4*)gp;
        if (g.x == -1.0f && mx.x == pc.x && pc.x > EPSF) {
            lsum += (double)(-__logf(1.0f - pc.x) * pc.x); csum += (double)pc.x;
        }
        if (g.y == -1.0f && mx.y == pc.y && pc.y > EPSF) {
            lsum += (double)(-__logf(1.0f - pc.y) * pc.y); csum += (double)pc.y;
        }
        if (g.z == -1.0f && mx.z == pc.z && pc.z > EPSF) {
            lsum += (double)(-__logf(1.0f - pc.z) * pc.z); csum += (double)pc.z;
        }
        if (g.w == -1.0f && mx.w == pc.w && pc.w > EPSF) {
            lsum += (double)(-__logf(1.0f - pc.w) * pc.w); csum += (double)pc.w;
        }
    }
}

// ws: [0..63] counter (zeroed by memset); slots at +64: NBLK x 6 doubles
// slot order: [loss_pos, loss_neg, loss_other, count_pos, count_neg, count_other]
__global__ __launch_bounds__(512) void fused_kernel(
    const float* __restrict__ lg0, const float* __restrict__ gt0, const int* __restrict__ c0,
    const float* __restrict__ lg1, const float* __restrict__ gt1, const int* __restrict__ c1,
    const float* __restrict__ wcls, double* __restrict__ slots,
    unsigned* __restrict__ counter, float* __restrict__ out) {
    __shared__ float pm[60 * 128];   // L0: 60 rows x 128; L1 reuses 24 rows x 64
    __shared__ double spart[48];
    __shared__ unsigned present[4];
    __shared__ bool isLast;
    int tid = threadIdx.x;
    int bid = blockIdx.x;
    double v0 = 0, v1 = 0, v2 = 0, v3 = 0, v4 = 0, v5 = 0;

    if (bid == 0) {
        // ---- pos path (both levels), 128 active threads ----
        if (tid < 4) present[tid] = 0u;
        __syncthreads();
        int lvl = (tid >> 6) & 1, tt = tid & 63;
        int b = tt >> 5, k = tt & 31;
        const float* lg = lvl ? lg1 : lg0;
        const float* gt = lvl ? gt1 : gt0;
        const int* cd = lvl ? c1 : c0;
        int D = lvl ? 32 : 64, H = lvl ? 64 : 128, Wd = lvl ? 64 : 128;
        int a = 0, d = 0, h = 0, w = 0, cls = 0;
        bool valid = false;
        size_t vol = (size_t)D * H * Wd, off = 0;
        if (tid < 128) {
            const int* c = cd + ((size_t)b * 32 + k) * 4;
            a = c[0]; d = c[1]; h = c[2]; w = c[3];
            valid = a > -1;
            if (!valid) { a = 0; d = 0; h = 0; w = 0; }
            off = ((size_t)d * H + h) * (size_t)Wd + w;
            float gval = gt[((size_t)b * 2 + a) * vol + off];
            cls = (int)gval - 1;
            cls = cls < 0 ? 0 : (cls > 3 ? 3 : cls);
            if (valid) atomicOr(&present[lvl * 2 + b], 1u << cls);
        }
        __syncthreads();
        if (tid < 128) {
            unsigned pmask = present[lvl * 2 + b];
            float vm = valid ? 1.0f : 0.0f;
            const float* lgb = lg + (size_t)b * 8 * vol;
            size_t aoff = (size_t)a * vol + off;
            float l_t = lgb[(size_t)cls * 2 * vol + aoff];
            float p_t = sigmoid_precise(l_t);
            float w_pos = (1.0f - p_t) * wcls[cls] * vm;
            float loss_pos = softplus(-l_t) * w_pos;  // -log_sigmoid(l_t)
            float ptg = (p_t > 0.5f) ? 1.0f : 0.0f;
            float lo = 0.0f, co = 0.0f;
#pragma unroll
            for (int cc = 0; cc < 4; cc++) {
                float l_o = lgb[(size_t)cc * 2 * vol + aoff];
                float p_o = sigmoid_precise(l_o);
                float wo = fmaxf(p_o - (p_t - 0.05f), 0.0f) * ((p_o > 0.5f) ? 1.0f : 0.0f) * ptg;
                float pres = ((pmask >> cc) & 1u) ? 1.0f : 0.0f;
                wo *= (1.0f - pres) * vm;
                lo += softplus(l_o) * wo;  // -log_sigmoid(-l_o)
                co += wo;
            }
            v0 = loss_pos; v3 = w_pos; v2 = lo; v5 = co;
        }
        __syncthreads();
    }

    // ---- neg path: every block does one L0 tile and one L1 quarter-tile ----
    neg_tile<128, 4, 8>(lg0, gt0, 64, 128, bid, pm, v1, v4);
    __syncthreads();
    neg_tile<64, 2, 4>(lg1, gt1, 32, 64, bid, pm, v1, v4);

    // ---- block reduction (double) ----
    for (int o = 32; o > 0; o >>= 1) {
        v0 += __shfl_down(v0, o); v1 += __shfl_down(v1, o); v2 += __shfl_down(v2, o);
        v3 += __shfl_down(v3, o); v4 += __shfl_down(v4, o); v5 += __shfl_down(v5, o);
    }
    int wave = tid >> 6, lane = tid & 63;
    if (lane == 0) {
        double* sp = spart + wave * 6;
        sp[0] = v0; sp[1] = v1; sp[2] = v2; sp[3] = v3; sp[4] = v4; sp[5] = v5;
    }
    __syncthreads();
    if (tid == 0) {
        double s[6] = {0, 0, 0, 0, 0, 0};
#pragma unroll
        for (int wv = 0; wv < 8; wv++)
#pragma unroll
            for (int j = 0; j < 6; j++) s[j] += spart[wv * 6 + j];
        double* slot = slots + (size_t)bid * 6;
#pragma unroll
        for (int j = 0; j < 6; j++) slot[j] = s[j];
        __threadfence();
        unsigned prev = atomicAdd(counter, 1u);
        isLast = (prev == NBLK - 1);
    }
    __syncthreads();
    if (isLast) {
        __threadfence();
        double acc[6] = {0, 0, 0, 0, 0, 0};
        for (int i = tid; i < NBLK; i += 512) {
            const double* sl = slots + (size_t)i * 6;
#pragma unroll
            for (int j = 0; j < 6; j++) acc[j] += sl[j];
        }
#pragma unroll
        for (int j = 0; j < 6; j++)
            for (int o = 32; o > 0; o >>= 1) acc[j] += __shfl_down(acc[j], o);
        __syncthreads();  // spart reuse
        if (lane == 0) {
            double* sp = spart + wave * 6;
#pragma unroll
            for (int j = 0; j < 6; j++) sp[j] = acc[j];
        }
        __syncthreads();
        if (tid == 0) {
#pragma unroll
            for (int j = 0; j < 6; j++) {
                double s = 0;
#pragma unroll
                for (int wv = 0; wv < 8; wv++) s += spart[wv * 6 + j];
                out[j] = (float)s;
            }
        }
    }
}

extern "C" void kernel_launch(void* const* d_in, const int* in_sizes, int n_in,
                              void* d_out, int out_size, void* d_ws, size_t ws_size,
                              hipStream_t stream) {
    const float *logits0 = nullptr, *gtprob0 = nullptr, *logits1 = nullptr,
                *gtprob1 = nullptr, *wcls = nullptr;
    const int *coords0 = nullptr, *coords1 = nullptr;
    for (int i = 0; i < n_in; i++) {
        switch (in_sizes[i]) {
            case 16777216: logits0 = (const float*)d_in[i]; break;   // 2*8*64*128*128
            case 4194304:  gtprob0 = (const float*)d_in[i]; break;   // 2*2*64*128*128
            case 2097152:  logits1 = (const float*)d_in[i]; break;   // 2*8*32*64*64
            case 524288:   gtprob1 = (const float*)d_in[i]; break;   // 2*2*32*64*64
            case 4:        wcls    = (const float*)d_in[i]; break;
            case 256:
                if (!coords0) coords0 = (const int*)d_in[i];
                else          coords1 = (const int*)d_in[i];
                break;
        }
    }
    unsigned* counter = (unsigned*)d_ws;
    double* slots = (double*)((char*)d_ws + 64);
    hipMemsetAsync(d_ws, 0, 64, stream);  // zero the completion counter
    fused_kernel<<<NBLK, 512, 0, stream>>>(logits0, gtprob0, coords0,
                                           logits1, gtprob1, coords1,
                                           wcls, slots, counter, (float*)d_out);
}

// Round 5
// 146.849 us; speedup vs baseline: 1.2299x; 1.1147x over previous
//
#include <hip/hip_runtime.h>
#include <math.h>

#define EPSF 1e-4f
#define NB_L1 128
#define NB_L0 1024
#define NBLK (NB_L1 + NB_L0)

static __device__ __forceinline__ float sigmoid_fast(float x) {
    float e = __expf(-x);
    float p = __builtin_amdgcn_rcpf(1.0f + e);
    return fminf(fmaxf(p, EPSF), 1.0f - EPSF);
}
static __device__ __forceinline__ float sigmoid_precise(float x) {
    float p = 1.0f / (1.0f + expf(-x));
    return fminf(fmaxf(p, EPSF), 1.0f - EPSF);
}
static __device__ __forceinline__ float softplus(float x) {
    return fmaxf(x, 0.0f) + log1pf(expf(-fabsf(x)));
}
static __device__ __forceinline__ float4 fmax4(float4 a, float4 b) {
    float4 r;
    r.x = fmaxf(a.x, b.x); r.y = fmaxf(a.y, b.y);
    r.z = fmaxf(a.z, b.z); r.w = fmaxf(a.w, b.w);
    return r;
}
static __device__ __forceinline__ float4 sig4(float4 x) {
    float4 r;
    r.x = sigmoid_fast(x.x); r.y = sigmoid_fast(x.y);
    r.z = sigmoid_fast(x.z); r.w = sigmoid_fast(x.w);
    return r;
}

// 3-wide w-window max of a quad from LDS; w-neighbors via lane shuffles.
// Group-edge lanes (w0==0 / WG-1) are true tensor edges (full-W tiles) => -inf.
template <int WG, int Wc>
static __device__ __forceinline__ float4 wmax_row(const float* pm, int row, int w0) {
    const float4 v = *(const float4*)(pm + (size_t)row * Wc + 4 * w0);
    float lft = __shfl_up(v.w, 1);
    float rgt = __shfl_down(v.x, 1);
    lft = (w0 == 0) ? -INFINITY : lft;
    rgt = (w0 == WG - 1) ? -INFINITY : rgt;
    float4 r;
    r.x = fmaxf(fmaxf(lft, v.x), v.y);
    r.y = fmaxf(fmaxf(v.x, v.y), v.z);
    r.z = fmaxf(fmaxf(v.y, v.z), v.w);
    r.w = fmaxf(fmaxf(v.z, v.w), rgt);
    return r;
}
template <int WG, int Wc>
static __device__ __forceinline__ float4 hfold(const float* pm, int row0, int w0) {
    return fmax4(fmax4(wmax_row<WG, Wc>(pm, row0, w0), wmax_row<WG, Wc>(pm, row0 + 1, w0)),
                 wmax_row<WG, Wc>(pm, row0 + 2, w0));
}

// One neg tile: TD(d) x TH(h) x Wc(w), 512 threads.
// Branchless clamped fill + 1-ahead register pipeline; gt prefetch before barrier.
template <int Wc, int TD, int TH, int D, int H>
static __device__ void neg_tile(const float* __restrict__ logits,
                                const float* __restrict__ gtprob,
                                int tileIdx, float* pm,
                                double& lsum, double& csum) {
    constexpr int WG = Wc / 4;
    constexpr int NROWH = TH + 2;
    constexpr int NROW = (TD + 2) * NROWH;
    constexpr int RPP = 512 / WG;                 // fill rows per pass
    constexpr int NPASS = (NROW + RPP - 1) / RPP;
    constexpr int NCELL = TD * TH;
    constexpr int CPT = (NCELL + RPP - 1) / RPP;  // compute cells per thread
    constexpr int NH = H / TH, ND = D / TD;
    const int ht = tileIdx % NH;
    const int dt = (tileIdx / NH) % ND;
    const int ab = tileIdx / (NH * ND);
    const int a = ab & 1, b = ab >> 1;
    const int h0 = ht * TH, d0 = dt * TD;
    const size_t HW = (size_t)H * Wc;
    const size_t vol = (size_t)D * HW;
    const float* lg = logits + ((size_t)b * 8 + a) * vol;  // channel = cls*2 + a
    const size_t cs = 2 * vol;
    const float* gtb = gtprob + ((size_t)b * 2 + a) * vol;
    const int tid = threadIdx.x;
    const int w0 = tid % WG, rg = tid / WG;

    // clamped row base + validity (loads always legal => unconditional => pipelinable)
    auto rowinfo = [&](int r, bool& inb) -> const float* {
        int rc = r < NROW - 1 ? r : NROW - 1;
        int rd = rc / NROWH, rh = rc - rd * NROWH;
        int d = d0 + rd - 1, h = h0 + rh - 1;
        inb = ((unsigned)d < (unsigned)D) & ((unsigned)h < (unsigned)H) & (r < NROW);
        int dc = d < 0 ? 0 : (d >= D ? D - 1 : d);
        int hc = h < 0 ? 0 : (h >= H ? H - 1 : h);
        return lg + (size_t)dc * HW + (size_t)hc * Wc + 4 * w0;
    };

    float4 n0, n1, n2, n3;
    bool ninb;
    {
        const float* p = rowinfo(rg, ninb);
        n0 = *(const float4*)p;            n1 = *(const float4*)(p + cs);
        n2 = *(const float4*)(p + 2 * cs); n3 = *(const float4*)(p + 3 * cs);
    }
#pragma unroll
    for (int ps = 0; ps < NPASS; ps++) {
        float4 c0 = n0, c1 = n1, c2 = n2, c3 = n3;
        bool inb = ninb;
        int r = rg + ps * RPP;
        if (ps + 1 < NPASS) {
            bool ib;
            const float* q = rowinfo(rg + (ps + 1) * RPP, ib);
            ninb = ib;
            n0 = *(const float4*)q;            n1 = *(const float4*)(q + cs);
            n2 = *(const float4*)(q + 2 * cs); n3 = *(const float4*)(q + 3 * cs);
        }
        float4 v = sig4(fmax4(fmax4(c0, c1), fmax4(c2, c3)));
        if (!inb) v = make_float4(-INFINITY, -INFINITY, -INFINITY, -INFINITY);
        if (r < NROW) *(float4*)(pm + (size_t)r * Wc + 4 * w0) = v;
    }

    // prefetch gt quads for this thread's compute cells (independent of LDS)
    float4 gq[CPT];
    int cdd[CPT], chh[CPT];
    bool cok[CPT];
#pragma unroll
    for (int k = 0; k < CPT; k++) {
        int cidx = rg + k * RPP;
        bool ok = cidx < NCELL;
        int ci = ok ? cidx : 0;
        int dd = ci / TH, hh = ci - dd * TH;
        cdd[k] = dd; chh[k] = hh; cok[k] = ok;
        gq[k] = *(const float4*)(gtb + (size_t)(d0 + dd) * HW + (size_t)(h0 + hh) * Wc + 4 * w0);
    }
    __syncthreads();

#pragma unroll
    for (int k = 0; k < CPT; k++) {
        if (!cok[k]) continue;  // wave-uniform (cell boundary aligns with wave boundary)
        int dd = cdd[k], hh = chh[k];
        float4 hm0 = hfold<WG, Wc>(pm, (dd + 0) * NROWH + hh, w0);
        float4 hm1 = hfold<WG, Wc>(pm, (dd + 1) * NROWH + hh, w0);
        float4 hm2 = hfold<WG, Wc>(pm, (dd + 2) * NROWH + hh, w0);
        float4 mx = fmax4(fmax4(hm0, hm1), hm2);
        float4 pc = *(const float4*)(pm + (size_t)((dd + 1) * NROWH + hh + 1) * Wc + 4 * w0);
        float4 g = gq[k];
        if (g.x == -1.0f && mx.x == pc.x && pc.x > EPSF) {
            lsum += (double)(-__logf(1.0f - pc.x) * pc.x); csum += (double)pc.x;
        }
        if (g.y == -1.0f && mx.y == pc.y && pc.y > EPSF) {
            lsum += (double)(-__logf(1.0f - pc.y) * pc.y); csum += (double)pc.y;
        }
        if (g.z == -1.0f && mx.z == pc.z && pc.z > EPSF) {
            lsum += (double)(-__logf(1.0f - pc.z) * pc.z); csum += (double)pc.z;
        }
        if (g.w == -1.0f && mx.w == pc.w && pc.w > EPSF) {
            lsum += (double)(-__logf(1.0f - pc.w) * pc.w); csum += (double)pc.w;
        }
    }
}

// gacc: 6 doubles [loss_pos, loss_neg, loss_other, count_pos, count_neg, count_other]
__global__ __launch_bounds__(512) void fused_kernel(
    const float* __restrict__ lg0, const float* __restrict__ gt0, const int* __restrict__ c0,
    const float* __restrict__ lg1, const float* __restrict__ gt1, const int* __restrict__ c1,
    const float* __restrict__ wcls, double* __restrict__ gacc) {
    __shared__ float pm[60 * 128];   // L0: 60x128; L1 reuses 100x64
    __shared__ double spart[48];
    __shared__ unsigned present[4];
    int tid = threadIdx.x;
    int bid = blockIdx.x;
    double v0 = 0, v1 = 0, v2 = 0, v3 = 0, v4 = 0, v5 = 0;

    if (bid >= NB_L1) {
        // ---- L0 tile ----
        neg_tile<128, 4, 8, 64, 128>(lg0, gt0, bid - NB_L1, pm, v1, v4);
    } else {
        if (bid == 0) {
            // ---- pos path (both levels), 128 active threads ----
            if (tid < 4) present[tid] = 0u;
            __syncthreads();
            int lvl = (tid >> 6) & 1, tt = tid & 63;
            int b = tt >> 5, k = tt & 31;
            const float* lg = lvl ? lg1 : lg0;
            const float* gt = lvl ? gt1 : gt0;
            const int* cd = lvl ? c1 : c0;
            int D = lvl ? 32 : 64, H = lvl ? 64 : 128, Wd = lvl ? 64 : 128;
            int a = 0, d = 0, h = 0, w = 0, cls = 0;
            bool valid = false;
            size_t vol = (size_t)D * H * Wd, off = 0;
            if (tid < 128) {
                const int* c = cd + ((size_t)b * 32 + k) * 4;
                a = c[0]; d = c[1]; h = c[2]; w = c[3];
                valid = a > -1;
                if (!valid) { a = 0; d = 0; h = 0; w = 0; }
                off = ((size_t)d * H + h) * (size_t)Wd + w;
                float gval = gt[((size_t)b * 2 + a) * vol + off];
                cls = (int)gval - 1;
                cls = cls < 0 ? 0 : (cls > 3 ? 3 : cls);
                if (valid) atomicOr(&present[lvl * 2 + b], 1u << cls);
            }
            __syncthreads();
            if (tid < 128) {
                unsigned pmask = present[lvl * 2 + b];
                float vm = valid ? 1.0f : 0.0f;
                const float* lgb = lg + (size_t)b * 8 * vol;
                size_t aoff = (size_t)a * vol + off;
                float l_t = lgb[(size_t)cls * 2 * vol + aoff];
                float p_t = sigmoid_precise(l_t);
                float w_pos = (1.0f - p_t) * wcls[cls] * vm;
                float loss_pos = softplus(-l_t) * w_pos;  // -log_sigmoid(l_t)
                float ptg = (p_t > 0.5f) ? 1.0f : 0.0f;
                float lo = 0.0f, co = 0.0f;
#pragma unroll
                for (int cc = 0; cc < 4; cc++) {
                    float l_o = lgb[(size_t)cc * 2 * vol + aoff];
                    float p_o = sigmoid_precise(l_o);
                    float wo = fmaxf(p_o - (p_t - 0.05f), 0.0f) * ((p_o > 0.5f) ? 1.0f : 0.0f) * ptg;
                    float pres = ((pmask >> cc) & 1u) ? 1.0f : 0.0f;
                    wo *= (1.0f - pres) * vm;
                    lo += softplus(l_o) * wo;  // -log_sigmoid(-l_o)
                    co += wo;
                }
                v0 = loss_pos; v3 = w_pos; v2 = lo; v5 = co;
            }
            __syncthreads();
        }
        // ---- L1 tile ----
        neg_tile<64, 8, 8, 32, 64>(lg1, gt1, bid, pm, v1, v4);
    }

    // ---- block reduction (double): v1,v4 everywhere; all six only in block 0 ----
    for (int o = 32; o > 0; o >>= 1) {
        v1 += __shfl_down(v1, o);
        v4 += __shfl_down(v4, o);
    }
    if (bid == 0) {
        for (int o = 32; o > 0; o >>= 1) {
            v0 += __shfl_down(v0, o); v2 += __shfl_down(v2, o);
            v3 += __shfl_down(v3, o); v5 += __shfl_down(v5, o);
        }
    }
    int wave = tid >> 6, lane = tid & 63;
    if (lane == 0) {
        double* sp = spart + wave * 6;
        sp[0] = v0; sp[1] = v1; sp[2] = v2; sp[3] = v3; sp[4] = v4; sp[5] = v5;
    }
    __syncthreads();
    if (tid == 0) {
        double s1 = 0, s4 = 0;
#pragma unroll
        for (int wv = 0; wv < 8; wv++) { s1 += spart[wv * 6 + 1]; s4 += spart[wv * 6 + 4]; }
        atomicAdd(&gacc[1], s1);
        atomicAdd(&gacc[4], s4);
        if (bid == 0) {
            double s0 = 0, s2 = 0, s3 = 0, s5 = 0;
#pragma unroll
            for (int wv = 0; wv < 8; wv++) {
                s0 += spart[wv * 6 + 0]; s2 += spart[wv * 6 + 2];
                s3 += spart[wv * 6 + 3]; s5 += spart[wv * 6 + 5];
            }
            atomicAdd(&gacc[0], s0); atomicAdd(&gacc[2], s2);
            atomicAdd(&gacc[3], s3); atomicAdd(&gacc[5], s5);
        }
    }
}

__global__ void finalize_kernel(const double* __restrict__ gacc, float* __restrict__ out) {
    int i = threadIdx.x;
    if (i < 6) out[i] = (float)gacc[i];
}

extern "C" void kernel_launch(void* const* d_in, const int* in_sizes, int n_in,
                              void* d_out, int out_size, void* d_ws, size_t ws_size,
                              hipStream_t stream) {
    const float *logits0 = nullptr, *gtprob0 = nullptr, *logits1 = nullptr,
                *gtprob1 = nullptr, *wcls = nullptr;
    const int *coords0 = nullptr, *coords1 = nullptr;
    for (int i = 0; i < n_in; i++) {
        switch (in_sizes[i]) {
            case 16777216: logits0 = (const float*)d_in[i]; break;   // 2*8*64*128*128
            case 4194304:  gtprob0 = (const float*)d_in[i]; break;   // 2*2*64*128*128
            case 2097152:  logits1 = (const float*)d_in[i]; break;   // 2*8*32*64*64
            case 524288:   gtprob1 = (const float*)d_in[i]; break;   // 2*2*32*64*64
            case 4:        wcls    = (const float*)d_in[i]; break;
            case 256:
                if (!coords0) coords0 = (const int*)d_in[i];
                else          coords1 = (const int*)d_in[i];
                break;
        }
    }
    double* gacc = (double*)d_ws;
    hipMemsetAsync(d_ws, 0, 6 * sizeof(double), stream);
    fused_kernel<<<NBLK, 512, 0, stream>>>(logits0, gtprob0, coords0,
                                           logits1, gtprob1, coords1,
                                           wcls, gacc);
    finalize_kernel<<<1, 64, 0, stream>>>(gacc, (float*)d_out);
}